// Round 3
// baseline (1467.491 us; speedup 1.0000x reference)
//
#include <hip/hip_runtime.h>
#include <hip/hip_fp16.h>
#include <cstdint>
#include <cstddef>

typedef __attribute__((ext_vector_type(8))) short short8;
typedef __attribute__((ext_vector_type(4))) float f32x4;

__device__ __forceinline__ float bf2f(unsigned short u) { return __uint_as_float(((unsigned)u) << 16); }
__device__ __forceinline__ unsigned short f2bf(float f) {
    unsigned u = __float_as_uint(f);
    return (unsigned short)((u + 0x7fffu + ((u >> 16) & 1u)) >> 16);
}

static constexpr float BN_INV = 0.9999950000374997f;  // 1/sqrt(1+1e-5)

// ---------------- voxelize: packed-f16 scatter-add into (130,130,130,4) channels-last grid --------
__global__ __launch_bounds__(256) void voxelize_kernel(const float4* __restrict__ pts,
                                                       __half2* __restrict__ grid, int N) {
    int i = blockIdx.x * 256 + threadIdx.x;
    if (i >= N) return;
    float4 p = pts[i];
    if (p.x < -32.f || p.x > 32.f || p.y < -32.f || p.y > 32.f || p.z < -32.f || p.z > 32.f) return;
    int cx = min(max((int)floorf((p.x + 32.f) * 2.f), 0), 127);
    int cy = min(max((int)floorf((p.y + 32.f) * 2.f), 0), 127);
    int cz = min(max((int)floorf((p.z + 32.f) * 2.f), 0), 127);
    int idx = ((((cz + 1) * 130) + (cy + 1)) * 130 + (cx + 1)) * 2;  // half2 units
    unsafeAtomicAdd(&grid[idx],     __floats2half2_rn(p.x, p.y));   // global_atomic_pk_add_f16
    unsafeAtomicAdd(&grid[idx + 1], __floats2half2_rn(p.z, p.w));
}

// f16 grid -> bf16 activations (2 elements / thread)
__global__ __launch_bounds__(256) void cvt_kernel(const __half2* __restrict__ g,
                                                  unsigned int* __restrict__ o, int n2) {
    int i = blockIdx.x * 256 + threadIdx.x;
    if (i >= n2) return;
    __half2 h = g[i];
    unsigned int lo = f2bf(__low2float(h));
    unsigned int hi = f2bf(__high2float(h));
    o[i] = lo | (hi << 16);
}

// ---------------- weight repacks (fold BN gamma scale) ----------------
// MFMA layers: out[k][co][ci] bf16
__global__ __launch_bounds__(256) void repack_w(const float* __restrict__ w, const float* __restrict__ g,
                                                unsigned short* __restrict__ o, int Co, int CI) {
    int i = blockIdx.x * 256 + threadIdx.x;
    int total = 27 * Co * CI;
    if (i >= total) return;
    int ci = i % CI;
    int t = i / CI;
    int co = t % Co;
    int k = t / Co;
    float v = w[((size_t)(co * CI + ci)) * 27 + k] * g[co] * BN_INV;
    o[i] = f2bf(v);
}
// conv1: out[k][ci][co] f32
__global__ __launch_bounds__(256) void repack_w1(const float* __restrict__ w, const float* __restrict__ g,
                                                 float* __restrict__ o) {
    int i = blockIdx.x * 256 + threadIdx.x;
    if (i >= 3456) return;
    int co = i % 32;
    int t = i / 32;
    int ci = t % 4;
    int k = t / 4;
    o[i] = w[(co * 4 + ci) * 27 + k] * g[co] * BN_INV;
}

// ---------------- conv1 direct: 4 -> 32 ch, stride 1, padded in (130^3,4), slab out ----------------
__global__ __launch_bounds__(256) void conv1_direct(
    const unsigned short* __restrict__ in, const float* __restrict__ wc,
    const float* __restrict__ beta, unsigned short* __restrict__ out,
    int zstart, int r0) {
    int p = blockIdx.x * 256 + threadIdx.x;
    int x0 = (p & 63) * 2;
    int ry = p >> 6;
    int y = ry & 127;
    int z = zstart + (ry >> 7);
    float acc0[32], acc1[32];
#pragma unroll
    for (int c = 0; c < 32; ++c) { acc0[c] = 0.f; acc1[c] = 0.f; }
#pragma unroll 1
    for (int dz = 0; dz < 3; ++dz) {
#pragma unroll 1
        for (int dy = 0; dy < 3; ++dy) {
            const unsigned short* rp = in + ((((z + dz) * 130) + (y + dy)) * 130 + x0) * 4;
            float f[16];
#pragma unroll
            for (int j = 0; j < 4; ++j) {
                uint2 d = *(const uint2*)(rp + j * 4);
                f[j * 4 + 0] = __uint_as_float(d.x << 16);
                f[j * 4 + 1] = __uint_as_float(d.x & 0xffff0000u);
                f[j * 4 + 2] = __uint_as_float(d.y << 16);
                f[j * 4 + 3] = __uint_as_float(d.y & 0xffff0000u);
            }
            const float* wb9 = wc + (dz * 3 + dy) * 3 * 4 * 32;
#pragma unroll
            for (int dx = 0; dx < 3; ++dx)
#pragma unroll
                for (int ci = 0; ci < 4; ++ci) {
                    const float* wrow = wb9 + (dx * 4 + ci) * 32;
                    float a0 = f[dx * 4 + ci];
                    float a1 = f[dx * 4 + ci + 4];
#pragma unroll
                    for (int co = 0; co < 32; ++co) {
                        acc0[co] = fmaf(a0, wrow[co], acc0[co]);
                        acc1[co] = fmaf(a1, wrow[co], acc1[co]);
                    }
                }
        }
    }
    int r = z - zstart + r0;
    unsigned short* op = out + (((r * 130) + (y + 1)) * 130 + (x0 + 1)) * 32;
#pragma unroll
    for (int j = 0; j < 8; ++j) {
        ushort4 u;
        u.x = f2bf(fmaxf(acc0[j * 4 + 0] + beta[j * 4 + 0], 0.f));
        u.y = f2bf(fmaxf(acc0[j * 4 + 1] + beta[j * 4 + 1], 0.f));
        u.z = f2bf(fmaxf(acc0[j * 4 + 2] + beta[j * 4 + 2], 0.f));
        u.w = f2bf(fmaxf(acc0[j * 4 + 3] + beta[j * 4 + 3], 0.f));
        *(ushort4*)(op + j * 4) = u;
    }
#pragma unroll
    for (int j = 0; j < 8; ++j) {
        ushort4 u;
        u.x = f2bf(fmaxf(acc1[j * 4 + 0] + beta[j * 4 + 0], 0.f));
        u.y = f2bf(fmaxf(acc1[j * 4 + 1] + beta[j * 4 + 1], 0.f));
        u.z = f2bf(fmaxf(acc1[j * 4 + 2] + beta[j * 4 + 2], 0.f));
        u.w = f2bf(fmaxf(acc1[j * 4 + 3] + beta[j * 4 + 3], 0.f));
        *(ushort4*)(op + 32 + j * 4) = u;
    }
}

// ---------------- MFMA implicit-GEMM conv, barrier-free: all fragments direct global->VGPR --------
// Block: 4 waves; wave tile = 64 co x 32 vox. A (weights) L1-broadcast across waves; B private.
// Flattened step loop s = k*(CI/32)+kc with 1-deep register prefetch; zero LDS, zero barriers.
template <int CI, int S>
__global__ __launch_bounds__(256) void conv_mfma(
    const unsigned short* __restrict__ in, const unsigned short* __restrict__ wb,
    const float* __restrict__ beta, unsigned short* __restrict__ out,
    int D, int lgD, int Xp, int Xpo, int Co, int zin_base, int v_off) {

    constexpr int NKC = CI / 32;
    constexpr int NSTEPS = 27 * NKC;
    const int tid = threadIdx.x;
    const int lane = tid & 63;
    const int wv = tid >> 6;
    const int m = lane & 15;
    const int q = lane >> 4;
    const int co0 = blockIdx.x * 64;
    const int v0 = v_off + blockIdx.y * 128 + wv * 32;

    int bgd[2];
#pragma unroll
    for (int vt = 0; vt < 2; ++vt) {
        int vg = v0 + vt * 16 + m;
        int x = vg & (D - 1);
        int ry = vg >> lgD;
        int y = ry & (D - 1);
        int z = ry >> lgD;
        bgd[vt] = ((z * S * Xp + y * S) * Xp + x * S) * CI + q * 8;
    }
    int ad[4];
#pragma unroll
    for (int cot = 0; cot < 4; ++cot) ad[cot] = (cot * 16 + m) * CI + q * 8;

    f32x4 acc[4][2];
#pragma unroll
    for (int cot = 0; cot < 4; ++cot)
#pragma unroll
        for (int vt = 0; vt < 2; ++vt) acc[cot][vt] = (f32x4){0.f, 0.f, 0.f, 0.f};

    auto loadstep = [&](int s, short8* a, short8* b) {
        int k = s / NKC;
        int kc = (s - k * NKC) * 32;
        int dz = k / 9;
        int rr = k - dz * 9;
        int dy = rr / 3;
        int dx = rr - dy * 3;
        int koff = (((dz - zin_base) * Xp + dy) * Xp + dx) * CI + kc;
        const unsigned short* wk = wb + (size_t)(k * Co + co0) * CI + kc;
#pragma unroll
        for (int cot = 0; cot < 4; ++cot) a[cot] = *(const short8*)(wk + ad[cot]);
#pragma unroll
        for (int vt = 0; vt < 2; ++vt) b[vt] = *(const short8*)(in + bgd[vt] + koff);
    };

    short8 a0[4], b0[2];
    loadstep(0, a0, b0);
#pragma unroll 2
    for (int s = 0; s < NSTEPS - 1; ++s) {
        short8 a1[4], b1[2];
        loadstep(s + 1, a1, b1);
#pragma unroll
        for (int cot = 0; cot < 4; ++cot)
#pragma unroll
            for (int vt = 0; vt < 2; ++vt)
                acc[cot][vt] = __builtin_amdgcn_mfma_f32_16x16x32_bf16(a0[cot], b0[vt], acc[cot][vt], 0, 0, 0);
#pragma unroll
        for (int j = 0; j < 4; ++j) a0[j] = a1[j];
        b0[0] = b1[0];
        b0[1] = b1[1];
    }
#pragma unroll
    for (int cot = 0; cot < 4; ++cot)
#pragma unroll
        for (int vt = 0; vt < 2; ++vt)
            acc[cot][vt] = __builtin_amdgcn_mfma_f32_16x16x32_bf16(a0[cot], b0[vt], acc[cot][vt], 0, 0, 0);

    // epilogue: relu(acc + beta) -> bf16, channels-last padded store
    float4 bt[4];
#pragma unroll
    for (int cot = 0; cot < 4; ++cot) bt[cot] = *(const float4*)(beta + co0 + cot * 16 + q * 4);
#pragma unroll
    for (int vt = 0; vt < 2; ++vt) {
        int vg = v0 + vt * 16 + m;
        int x = vg & (D - 1);
        int ry = vg >> lgD;
        int y = ry & (D - 1);
        int z = ry >> lgD;
        size_t ob = (((size_t)(z + 1) * Xpo + (y + 1)) * Xpo + (x + 1)) * Co + co0;
#pragma unroll
        for (int cot = 0; cot < 4; ++cot) {
            f32x4 v = acc[cot][vt];
            ushort4 u;
            u.x = f2bf(fmaxf(v.x + bt[cot].x, 0.f));
            u.y = f2bf(fmaxf(v.y + bt[cot].y, 0.f));
            u.z = f2bf(fmaxf(v.z + bt[cot].z, 0.f));
            u.w = f2bf(fmaxf(v.w + bt[cot].w, 0.f));
            *(ushort4*)(out + ob + cot * 16 + q * 4) = u;
        }
    }
}

// ---------------- BEV max over y: O6p (34,34,34,256) -> bev[(z*32+x)*256+c] f32 ----------------
__global__ __launch_bounds__(256) void bev_max_kernel(const unsigned short* __restrict__ feat,
                                                      float* __restrict__ bev) {
    int z = blockIdx.x >> 5;
    int x = blockIdx.x & 31;
    int c = threadIdx.x;
    const unsigned short* p = feat + ((((z + 1) * 34) + 1) * 34 + (x + 1)) * 256 + c;
    float mx = 0.f;  // post-ReLU values are >= 0
#pragma unroll
    for (int y = 0; y < 32; ++y) mx = fmaxf(mx, bf2f(p[y * 34 * 256]));
    bev[(z * 32 + x) * 256 + c] = mx;
}

// ---------------- bilinear resize 32x32 -> 200x200, half-pixel, edge clamp ----------------
__global__ __launch_bounds__(256) void resize_kernel(const float* __restrict__ bev,
                                                     float* __restrict__ out) {
    int i = blockIdx.x * 256 + threadIdx.x;
    if (i >= 256 * 200 * 200) return;
    int ox = i % 200;
    int t = i / 200;
    int oy = t % 200;
    int c = t / 200;
    const float sc = 32.0f / 200.0f;
    float fy = (oy + 0.5f) * sc - 0.5f;
    float fx = (ox + 0.5f) * sc - 0.5f;
    float fy0 = floorf(fy), fx0 = floorf(fx);
    float ty = fy - fy0, tx = fx - fx0;
    int y0 = min(max((int)fy0, 0), 31), y1 = min(max((int)fy0 + 1, 0), 31);
    int x0 = min(max((int)fx0, 0), 31), x1 = min(max((int)fx0 + 1, 0), 31);
    float v00 = bev[(y0 * 32 + x0) * 256 + c], v01 = bev[(y0 * 32 + x1) * 256 + c];
    float v10 = bev[(y1 * 32 + x0) * 256 + c], v11 = bev[(y1 * 32 + x1) * 256 + c];
    float top = v00 + tx * (v01 - v00);
    float bot = v10 + tx * (v11 - v10);
    out[i] = top + ty * (bot - top);
}

extern "C" void kernel_launch(void* const* d_in, const int* in_sizes, int n_in,
                              void* d_out, int out_size, void* d_ws, size_t ws_size,
                              hipStream_t stream) {
    const float* points = (const float*)d_in[0];
    int N = in_sizes[0] / 4;
    const float *W[6], *G[6], *B[6];
    for (int i = 0; i < 6; ++i) {
        W[i] = (const float*)d_in[1 + 3 * i];
        G[i] = (const float*)d_in[2 + 3 * i];
        B[i] = (const float*)d_in[3 + 3 * i];
    }

    // ---- workspace layout (bytes), peak ~144 MiB (ws >= 161 MiB proven in round 0) ----
    char* ws = (char*)d_ws;
    const size_t MiB = 1ull << 20;
    __half2* gridH = (__half2*)(ws);                             // 130^3*4*2 = 17,576,000
    unsigned short* X0p = (unsigned short*)(ws + 18 * MiB);      // 17,576,000
    unsigned short* O1s = (unsigned short*)(ws + 36 * MiB);      // 65*130*130*32*2 = 70,304,000
    unsigned short* O2p = (unsigned short*)(ws + 104 * MiB);     // 66^3*64*2 = 36,799,488
    unsigned short* O3p = (unsigned short*)(ws);                 // 36,799,488 (over dead gridH/X0p)
    unsigned short* O4p = (unsigned short*)(ws + 36 * MiB);      // 34^3*128*2 = 10,061,824 (over dead O1s)
    unsigned short* O5p = (unsigned short*)(ws + 47 * MiB);      // 10,061,824
    unsigned short* O6p = (unsigned short*)(ws + 58 * MiB);      // 34^3*256*2 = 20,123,648
    float* bev = (float*)(ws + 79 * MiB);                        // 1,048,576
    float* wc1 = (float*)(ws + 140 * MiB);                       // 13,824
    unsigned short* wb2 = (unsigned short*)(ws + 140 * MiB + 16384);
    unsigned short* wb3 = wb2 + 27 * 64 * 32;
    unsigned short* wb4 = wb3 + 27 * 64 * 64;
    unsigned short* wb5 = wb4 + 27 * 128 * 64;
    unsigned short* wb6 = wb5 + 27 * 128 * 128;

    // weight repacks (independent of activations)
    repack_w1<<<14, 256, 0, stream>>>(W[0], G[0], wc1);
    repack_w<<<216, 256, 0, stream>>>(W[1], G[1], wb2, 64, 32);
    repack_w<<<432, 256, 0, stream>>>(W[2], G[2], wb3, 64, 64);
    repack_w<<<864, 256, 0, stream>>>(W[3], G[3], wb4, 128, 64);
    repack_w<<<1728, 256, 0, stream>>>(W[4], G[4], wb5, 128, 128);
    repack_w<<<3456, 256, 0, stream>>>(W[5], G[5], wb6, 256, 128);

    // voxelize (f16 pk atomics) -> bf16 padded channels-last
    hipMemsetAsync(gridH, 0, 17576000, stream);
    hipMemsetAsync(O2p, 0, 36799488, stream);
    voxelize_kernel<<<(N + 255) / 256, 256, 0, stream>>>((const float4*)points, gridH, N);
    cvt_kernel<<<17165, 256, 0, stream>>>(gridH, (unsigned int*)X0p, 4394000);

    // conv1/conv2 in two z-slabs (O1s holds 65 padded-z rows)
    hipMemsetAsync(O1s, 0, 70304000, stream);
    conv1_direct<<<2048, 256, 0, stream>>>(X0p, wc1, B[0], O1s, 0, 1);
    conv_mfma<32, 2><<<dim3(1, 1024), 256, 0, stream>>>(O1s, wb2, B[1], O2p, 64, 6, 130, 66, 64, 0, 0);
    conv1_direct<<<2080, 256, 0, stream>>>(X0p, wc1, B[0], O1s, 63, 0);
    conv_mfma<32, 2><<<dim3(1, 1024), 256, 0, stream>>>(O1s, wb2, B[1], O2p, 64, 6, 130, 66, 64, 64, 131072);

    // remaining buffers become free only after conv2-h2
    hipMemsetAsync(O3p, 0, 36799488, stream);
    hipMemsetAsync(O4p, 0, 10061824, stream);
    hipMemsetAsync(O5p, 0, 10061824, stream);
    hipMemsetAsync(O6p, 0, 20123648, stream);

    // conv3: 64->64, s1, 64^3
    conv_mfma<64, 1><<<dim3(1, 2048), 256, 0, stream>>>(O2p, wb3, B[2], O3p, 64, 6, 66, 66, 64, 0, 0);
    // conv4: 64->128, s2, 64^3 -> 32^3
    conv_mfma<64, 2><<<dim3(2, 256), 256, 0, stream>>>(O3p, wb4, B[3], O4p, 32, 5, 66, 34, 128, 0, 0);
    // conv5: 128->128, s1, 32^3
    conv_mfma<128, 1><<<dim3(2, 256), 256, 0, stream>>>(O4p, wb5, B[4], O5p, 32, 5, 34, 34, 128, 0, 0);
    // conv6: 128->256, s1, 32^3
    conv_mfma<128, 1><<<dim3(4, 256), 256, 0, stream>>>(O5p, wb6, B[5], O6p, 32, 5, 34, 34, 256, 0, 0);

    bev_max_kernel<<<1024, 256, 0, stream>>>(O6p, bev);
    resize_kernel<<<40000, 256, 0, stream>>>(bev, (float*)d_out);
}

// Round 4
// 1400.368 us; speedup vs baseline: 1.0479x; 1.0479x over previous
//
#include <hip/hip_runtime.h>
#include <hip/hip_fp16.h>
#include <cstdint>
#include <cstddef>

typedef __attribute__((ext_vector_type(8))) short short8;
typedef __attribute__((ext_vector_type(8))) _Float16 half8;
typedef __attribute__((ext_vector_type(16))) float f32x16;

__device__ __forceinline__ float bf2f(unsigned short u) { return __uint_as_float(((unsigned)u) << 16); }
__device__ __forceinline__ unsigned short f2bf(float f) {
    unsigned u = __float_as_uint(f);
    return (unsigned short)((u + 0x7fffu + ((u >> 16) & 1u)) >> 16);
}

static constexpr float BN_INV = 0.9999950000374997f;  // 1/sqrt(1+1e-5)

// ---------------- voxelize: packed-f16 scatter-add into (130,130,130,4) channels-last grid --------
__global__ __launch_bounds__(256) void voxelize_kernel(const float4* __restrict__ pts,
                                                       __half2* __restrict__ grid, int N) {
    int i = blockIdx.x * 256 + threadIdx.x;
    if (i >= N) return;
    float4 p = pts[i];
    if (p.x < -32.f || p.x > 32.f || p.y < -32.f || p.y > 32.f || p.z < -32.f || p.z > 32.f) return;
    int cx = min(max((int)floorf((p.x + 32.f) * 2.f), 0), 127);
    int cy = min(max((int)floorf((p.y + 32.f) * 2.f), 0), 127);
    int cz = min(max((int)floorf((p.z + 32.f) * 2.f), 0), 127);
    int idx = ((((cz + 1) * 130) + (cy + 1)) * 130 + (cx + 1)) * 2;  // half2 units
    unsafeAtomicAdd(&grid[idx],     __floats2half2_rn(p.x, p.y));   // global_atomic_pk_add_f16
    unsafeAtomicAdd(&grid[idx + 1], __floats2half2_rn(p.z, p.w));
}

// ---------------- weight repacks (fold BN gamma scale) ----------------
// MFMA layers 2-6: out[k][co][ci] bf16
__global__ __launch_bounds__(256) void repack_w(const float* __restrict__ w, const float* __restrict__ g,
                                                unsigned short* __restrict__ o, int Co, int CI) {
    int i = blockIdx.x * 256 + threadIdx.x;
    int total = 27 * Co * CI;
    if (i >= total) return;
    int ci = i % CI;
    int t = i / CI;
    int co = t % Co;
    int k = t / Co;
    float v = w[((size_t)(co * CI + ci)) * 27 + k] * g[co] * BN_INV;
    o[i] = f2bf(v);
}
// conv1 MFMA: out[pair p(9)][co(32)][k16] f16, k16 = dx*4+ci for k16<12 else 0
__global__ __launch_bounds__(256) void repack_w1m(const float* __restrict__ w, const float* __restrict__ g,
                                                  unsigned short* __restrict__ o) {
    int i = blockIdx.x * 256 + threadIdx.x;
    if (i >= 9 * 32 * 16) return;
    int k16 = i & 15;
    int co = (i >> 4) & 31;
    int p = i >> 9;
    float v = 0.f;
    if (k16 < 12) {
        int dx = k16 >> 2, ci = k16 & 3;
        int dz = p / 3, dy = p % 3;
        v = w[(co * 4 + ci) * 27 + dz * 9 + dy * 3 + dx] * g[co] * BN_INV;
    }
    o[i] = __half_as_ushort(__float2half(v));
}

// ---------------- conv1 via MFMA 32x32x16_f16 on the f16 grid ----------------
// wave tile: 32 co (all) x 32 vox. 9 steps = (dz,dy) pairs, K=16 = (dx,ci) 12 real + 4 pad.
// A-side zeros at k>=12 annihilate B's garbage lanes, so B loads need no masking.
__global__ __launch_bounds__(256) void conv1_mfma(
    const unsigned short* __restrict__ in, const unsigned short* __restrict__ wa,
    const float* __restrict__ beta, unsigned short* __restrict__ out,
    int zstart, int r0) {
    const int tid = threadIdx.x;
    const int l31 = tid & 31;
    const int lh = (tid >> 5) & 1;
    const int wv = tid >> 6;
    int v = blockIdx.x * 128 + wv * 32 + l31;
    int x = v & 127;
    int y = (v >> 7) & 127;
    int z = zstart + (v >> 14);

    f32x16 acc = {0.f};
#pragma unroll
    for (int p = 0; p < 9; ++p) {
        int dz = p / 3, dy = p % 3;
        const unsigned short* rp = in + (((z + dz) * 130 + (y + dy)) * 130 + x) * 4 + lh * 8;
        uint2 d0 = *(const uint2*)(rp);
        uint2 d1 = *(const uint2*)(rp + 4);  // for lh=1 these are k12-15: annihilated by A zeros
        uint4 braw = {d0.x, d0.y, d1.x, d1.y};
        half8 b = *(half8*)&braw;
        half8 a = *(const half8*)(wa + (p * 32 + l31) * 16 + lh * 8);
        acc = __builtin_amdgcn_mfma_f32_32x32x16_f16(a, b, acc, 0, 0, 0);
    }
    int r = z - zstart + r0;
    int ob = ((r * 130 + (y + 1)) * 130 + (x + 1)) * 32;
#pragma unroll
    for (int g = 0; g < 4; ++g) {
        int cb = 4 * lh + 8 * g;
        float4 bt = *(const float4*)(beta + cb);
        ushort4 u;
        u.x = f2bf(fmaxf(acc[g * 4 + 0] + bt.x, 0.f));
        u.y = f2bf(fmaxf(acc[g * 4 + 1] + bt.y, 0.f));
        u.z = f2bf(fmaxf(acc[g * 4 + 2] + bt.z, 0.f));
        u.w = f2bf(fmaxf(acc[g * 4 + 3] + bt.w, 0.f));
        *(ushort4*)(out + ob + cb) = u;
    }
}

// ---------------- convs 2-6: barrier-free MFMA implicit GEMM, 32x32x16 bf16 ----------------
// wave tile: 64 co x 32 vox. Fully unrolled step loop (k-offset x ci-chunk); B frags triple-
// buffered, A frags double-buffered in registers -> fine-grained per-use vmcnt, no barriers.
template <int CI, int KC, int S>
__global__ __launch_bounds__(256) void conv_mfma(
    const unsigned short* __restrict__ in, const unsigned short* __restrict__ wb,
    const float* __restrict__ beta, unsigned short* __restrict__ out,
    int D, int lgD, int Xp, int Xpo, int Co, int zin_base, int v_off) {

    constexpr int NCH = KC / 16;   // k16 chunks per step
    constexpr int NCC = CI / KC;   // ci chunks per k-offset
    constexpr int STOT = 27 * NCC;

    const int tid = threadIdx.x;
    const int l31 = tid & 31;
    const int lh = (tid >> 5) & 1;
    const int wv = tid >> 6;
    const int co0 = blockIdx.x * 64;

    int vg = v_off + blockIdx.y * 128 + wv * 32 + l31;
    int x = vg & (D - 1);
    int ry = vg >> lgD;
    int y = ry & (D - 1);
    int z = ry >> lgD;
    const int vbase = ((z * S * Xp + y * S) * Xp + x * S) * CI + lh * 8;

    int abase0 = (co0 + l31) * CI + lh * 8;
    int abase1 = abase0 + 32 * CI;

    auto koffset = [&](int s) -> int {
        int k = s / NCC;
        int c0 = (s - k * NCC) * KC;
        int dz = k / 9;
        int rr = k - dz * 9;
        int dy = rr / 3;
        int dx = rr - dy * 3;
        return (((dz - zin_base) * Xp + dy) * Xp + dx) * CI + c0;
    };

    short8 bB[3][NCH];
    short8 aB[2][2][NCH];

    auto loadB = [&](int s, int slot) {
        int ko = vbase + koffset(s);
#pragma unroll
        for (int c = 0; c < NCH; ++c) bB[slot][c] = *(const short8*)(in + ko + c * 16);
    };
    auto loadA = [&](int s, int slot) {
        int k = s / NCC;
        int c0 = (s - k * NCC) * KC;
        int wk = k * Co * CI + c0;
#pragma unroll
        for (int c = 0; c < NCH; ++c) {
            aB[slot][0][c] = *(const short8*)(wb + wk + abase0 + c * 16);
            aB[slot][1][c] = *(const short8*)(wb + wk + abase1 + c * 16);
        }
    };

    f32x16 acc0 = {0.f}, acc1 = {0.f};

    loadB(0, 0); loadB(1, 1);
    loadA(0, 0); loadA(1, 1);
    loadB(2, 2);

#pragma unroll
    for (int s = 0; s < STOT; ++s) {
        const int m2 = s % 2, m3 = s % 3;
#pragma unroll
        for (int c = 0; c < NCH; ++c) {
            acc0 = __builtin_amdgcn_mfma_f32_32x32x16_bf16(aB[m2][0][c], bB[m3][c], acc0, 0, 0, 0);
            acc1 = __builtin_amdgcn_mfma_f32_32x32x16_bf16(aB[m2][1][c], bB[m3][c], acc1, 0, 0, 0);
        }
        if (s + 2 < STOT) loadA(s + 2, m2);
        if (s + 3 < STOT) loadB(s + 3, m3);
    }

    // epilogue: relu(acc + beta) -> bf16, channels-last padded store
    size_t ob = (((size_t)(z + 1) * Xpo + (y + 1)) * Xpo + (x + 1)) * Co + co0;
#pragma unroll
    for (int cot = 0; cot < 2; ++cot) {
        const f32x16& a = cot ? acc1 : acc0;
#pragma unroll
        for (int g = 0; g < 4; ++g) {
            int cb = cot * 32 + 4 * lh + 8 * g;
            float4 bt = *(const float4*)(beta + co0 + cb);
            ushort4 u;
            u.x = f2bf(fmaxf(a[g * 4 + 0] + bt.x, 0.f));
            u.y = f2bf(fmaxf(a[g * 4 + 1] + bt.y, 0.f));
            u.z = f2bf(fmaxf(a[g * 4 + 2] + bt.z, 0.f));
            u.w = f2bf(fmaxf(a[g * 4 + 3] + bt.w, 0.f));
            *(ushort4*)(out + ob + cb) = u;
        }
    }
}

// ---------------- BEV max over y: O6p (34,34,34,256) -> bev[(z*32+x)*256+c] f32 ----------------
__global__ __launch_bounds__(256) void bev_max_kernel(const unsigned short* __restrict__ feat,
                                                      float* __restrict__ bev) {
    int z = blockIdx.x >> 5;
    int x = blockIdx.x & 31;
    int c = threadIdx.x;
    const unsigned short* p = feat + ((((z + 1) * 34) + 1) * 34 + (x + 1)) * 256 + c;
    float mx = 0.f;  // post-ReLU values are >= 0
#pragma unroll
    for (int y = 0; y < 32; ++y) mx = fmaxf(mx, bf2f(p[y * 34 * 256]));
    bev[(z * 32 + x) * 256 + c] = mx;
}

// ---------------- bilinear resize 32x32 -> 200x200, half-pixel, edge clamp ----------------
__global__ __launch_bounds__(256) void resize_kernel(const float* __restrict__ bev,
                                                     float* __restrict__ out) {
    int i = blockIdx.x * 256 + threadIdx.x;
    if (i >= 256 * 200 * 200) return;
    int ox = i % 200;
    int t = i / 200;
    int oy = t % 200;
    int c = t / 200;
    const float sc = 32.0f / 200.0f;
    float fy = (oy + 0.5f) * sc - 0.5f;
    float fx = (ox + 0.5f) * sc - 0.5f;
    float fy0 = floorf(fy), fx0 = floorf(fx);
    float ty = fy - fy0, tx = fx - fx0;
    int y0 = min(max((int)fy0, 0), 31), y1 = min(max((int)fy0 + 1, 0), 31);
    int x0 = min(max((int)fx0, 0), 31), x1 = min(max((int)fx0 + 1, 0), 31);
    float v00 = bev[(y0 * 32 + x0) * 256 + c], v01 = bev[(y0 * 32 + x1) * 256 + c];
    float v10 = bev[(y1 * 32 + x0) * 256 + c], v11 = bev[(y1 * 32 + x1) * 256 + c];
    float top = v00 + tx * (v01 - v00);
    float bot = v10 + tx * (v11 - v10);
    out[i] = top + ty * (bot - top);
}

extern "C" void kernel_launch(void* const* d_in, const int* in_sizes, int n_in,
                              void* d_out, int out_size, void* d_ws, size_t ws_size,
                              hipStream_t stream) {
    const float* points = (const float*)d_in[0];
    int N = in_sizes[0] / 4;
    const float *W[6], *G[6], *B[6];
    for (int i = 0; i < 6; ++i) {
        W[i] = (const float*)d_in[1 + 3 * i];
        G[i] = (const float*)d_in[2 + 3 * i];
        B[i] = (const float*)d_in[3 + 3 * i];
    }

    // ---- workspace layout (bytes), peak ~144 MiB ----
    char* ws = (char*)d_ws;
    const size_t MiB = 1ull << 20;
    unsigned short* gridH = (unsigned short*)(ws);               // f16 (130^3,4) = 17,576,000 B
    unsigned short* O1s = (unsigned short*)(ws + 18 * MiB);      // 65*130*130*32*2 = 70,304,000
    unsigned short* O2p = (unsigned short*)(ws + 104 * MiB);     // 66^3*64*2 = 36,799,488
    unsigned short* O3p = (unsigned short*)(ws);                 // 36,799,488 (over dead gridH/O1s-head)
    unsigned short* O4p = (unsigned short*)(ws + 37 * MiB);      // 34^3*128*2 = 10,061,824
    unsigned short* O5p = (unsigned short*)(ws + 48 * MiB);      // 10,061,824
    unsigned short* O6p = (unsigned short*)(ws + 59 * MiB);      // 34^3*256*2 = 20,123,648
    float* bev = (float*)(ws + 80 * MiB);                        // 1,048,576
    unsigned short* wc1 = (unsigned short*)(ws + 140 * MiB);     // 9*32*16*2 = 9,216
    unsigned short* wb2 = (unsigned short*)(ws + 140 * MiB + 16384);
    unsigned short* wb3 = wb2 + 27 * 64 * 32;
    unsigned short* wb4 = wb3 + 27 * 64 * 64;
    unsigned short* wb5 = wb4 + 27 * 128 * 64;
    unsigned short* wb6 = wb5 + 27 * 128 * 128;

    // weight repacks (independent of activations)
    repack_w1m<<<18, 256, 0, stream>>>(W[0], G[0], wc1);
    repack_w<<<216, 256, 0, stream>>>(W[1], G[1], wb2, 64, 32);
    repack_w<<<432, 256, 0, stream>>>(W[2], G[2], wb3, 64, 64);
    repack_w<<<864, 256, 0, stream>>>(W[3], G[3], wb4, 128, 64);
    repack_w<<<1728, 256, 0, stream>>>(W[4], G[4], wb5, 128, 128);
    repack_w<<<3456, 256, 0, stream>>>(W[5], G[5], wb6, 256, 128);

    // voxelize (f16 pk atomics)
    hipMemsetAsync(gridH, 0, 17576000, stream);
    hipMemsetAsync(O2p, 0, 36799488, stream);
    voxelize_kernel<<<(N + 255) / 256, 256, 0, stream>>>((const float4*)points, (__half2*)gridH, N);

    // conv1/conv2 in two z-slabs (O1s holds 65 padded-z rows)
    hipMemsetAsync(O1s, 0, 70304000, stream);
    conv1_mfma<<<8192, 256, 0, stream>>>(gridH, wc1, B[0], O1s, 0, 1);
    conv_mfma<32, 32, 2><<<dim3(1, 1024), 256, 0, stream>>>(O1s, wb2, B[1], O2p, 64, 6, 130, 66, 64, 0, 0);
    conv1_mfma<<<8320, 256, 0, stream>>>(gridH, wc1, B[0], O1s, 63, 0);
    conv_mfma<32, 32, 2><<<dim3(1, 1024), 256, 0, stream>>>(O1s, wb2, B[1], O2p, 64, 6, 130, 66, 64, 64, 131072);

    // remaining buffers become free only after conv2-h2
    hipMemsetAsync(O3p, 0, 36799488, stream);
    hipMemsetAsync(O4p, 0, 10061824, stream);
    hipMemsetAsync(O5p, 0, 10061824, stream);
    hipMemsetAsync(O6p, 0, 20123648, stream);

    // conv3: 64->64, s1, 64^3
    conv_mfma<64, 64, 1><<<dim3(1, 2048), 256, 0, stream>>>(O2p, wb3, B[2], O3p, 64, 6, 66, 66, 64, 0, 0);
    // conv4: 64->128, s2, 64^3 -> 32^3
    conv_mfma<64, 64, 2><<<dim3(2, 256), 256, 0, stream>>>(O3p, wb4, B[3], O4p, 32, 5, 66, 34, 128, 0, 0);
    // conv5: 128->128, s1, 32^3
    conv_mfma<128, 64, 1><<<dim3(2, 256), 256, 0, stream>>>(O4p, wb5, B[4], O5p, 32, 5, 34, 34, 128, 0, 0);
    // conv6: 128->256, s1, 32^3
    conv_mfma<128, 64, 1><<<dim3(4, 256), 256, 0, stream>>>(O5p, wb6, B[5], O6p, 32, 5, 34, 34, 256, 0, 0);

    bev_max_kernel<<<1024, 256, 0, stream>>>(O6p, bev);
    resize_kernel<<<40000, 256, 0, stream>>>(bev, (float*)d_out);
}

// Round 5
// 759.284 us; speedup vs baseline: 1.9327x; 1.8443x over previous
//
#include <hip/hip_runtime.h>
#include <hip/hip_fp16.h>
#include <cstdint>
#include <cstddef>

typedef __attribute__((ext_vector_type(8))) short short8;
typedef __attribute__((ext_vector_type(8))) _Float16 half8;
typedef __attribute__((ext_vector_type(16))) float f32x16;

__device__ __forceinline__ float bf2f(unsigned short u) { return __uint_as_float(((unsigned)u) << 16); }
__device__ __forceinline__ unsigned short f2bf(float f) {
    unsigned u = __float_as_uint(f);
    return (unsigned short)((u + 0x7fffu + ((u >> 16) & 1u)) >> 16);
}
// CK-style: drain LDS counters only, leave vmcnt live across the barrier
__device__ __forceinline__ void sync_lds() {
    asm volatile("s_waitcnt lgkmcnt(0)\n\ts_barrier" ::: "memory");
}

static constexpr float BN_INV = 0.9999950000374997f;  // 1/sqrt(1+1e-5)

// ---------------- voxelize: packed-f16 scatter-add into (130,130,130,4) channels-last grid --------
__global__ __launch_bounds__(256) void voxelize_kernel(const float4* __restrict__ pts,
                                                       __half2* __restrict__ grid, int N) {
    int i = blockIdx.x * 256 + threadIdx.x;
    if (i >= N) return;
    float4 p = pts[i];
    if (p.x < -32.f || p.x > 32.f || p.y < -32.f || p.y > 32.f || p.z < -32.f || p.z > 32.f) return;
    int cx = min(max((int)floorf((p.x + 32.f) * 2.f), 0), 127);
    int cy = min(max((int)floorf((p.y + 32.f) * 2.f), 0), 127);
    int cz = min(max((int)floorf((p.z + 32.f) * 2.f), 0), 127);
    int idx = ((((cz + 1) * 130) + (cy + 1)) * 130 + (cx + 1)) * 2;  // half2 units
    unsafeAtomicAdd(&grid[idx],     __floats2half2_rn(p.x, p.y));   // global_atomic_pk_add_f16
    unsafeAtomicAdd(&grid[idx + 1], __floats2half2_rn(p.z, p.w));
}

// ---------------- weight repacks (fold BN gamma scale) ----------------
__global__ __launch_bounds__(256) void repack_w(const float* __restrict__ w, const float* __restrict__ g,
                                                unsigned short* __restrict__ o, int Co, int CI) {
    int i = blockIdx.x * 256 + threadIdx.x;
    int total = 27 * Co * CI;
    if (i >= total) return;
    int ci = i % CI;
    int t = i / CI;
    int co = t % Co;
    int k = t / Co;
    float v = w[((size_t)(co * CI + ci)) * 27 + k] * g[co] * BN_INV;
    o[i] = f2bf(v);
}
// conv1 MFMA: out[pair p(9)][co(32)][k16] f16, k16 = dx*4+ci for k16<12 else 0
__global__ __launch_bounds__(256) void repack_w1m(const float* __restrict__ w, const float* __restrict__ g,
                                                  unsigned short* __restrict__ o) {
    int i = blockIdx.x * 256 + threadIdx.x;
    if (i >= 9 * 32 * 16) return;
    int k16 = i & 15;
    int co = (i >> 4) & 31;
    int p = i >> 9;
    float v = 0.f;
    if (k16 < 12) {
        int dx = k16 >> 2, ci = k16 & 3;
        int dz = p / 3, dy = p % 3;
        v = w[(co * 4 + ci) * 27 + dz * 9 + dy * 3 + dx] * g[co] * BN_INV;
    }
    o[i] = __half_as_ushort(__float2half(v));
}

// ---------------- conv1 via MFMA 32x32x16_f16, all 27 fragment loads preissued ----------------
__global__ __launch_bounds__(256) void conv1_mfma(
    const unsigned short* __restrict__ in, const unsigned short* __restrict__ wa,
    const float* __restrict__ beta, unsigned short* __restrict__ out,
    int zstart, int r0) {
    const int tid = threadIdx.x;
    const int l31 = tid & 31;
    const int lh = (tid >> 5) & 1;
    const int wv = tid >> 6;
    int v = blockIdx.x * 128 + wv * 32 + l31;
    int x = v & 127;
    int y = (v >> 7) & 127;
    int z = zstart + (v >> 14);

    const unsigned short* base = in + ((z * 130 + y) * 130 + x) * 4 + lh * 8;
    uint2 d0[9], d1[9];
    half8 a[9];
#pragma unroll
    for (int p = 0; p < 9; ++p) {
        int dz = p / 3, dy = p % 3;
        const unsigned short* rp = base + (dz * 130 + dy) * 520;
        d0[p] = *(const uint2*)(rp);
        d1[p] = *(const uint2*)(rp + 4);  // lh=1: k12-15 garbage, annihilated by A zeros
        a[p] = *(const half8*)(wa + (p * 32 + l31) * 16 + lh * 8);
    }
    f32x16 acc = {0.f};
#pragma unroll
    for (int p = 0; p < 9; ++p) {
        uint4 braw = {d0[p].x, d0[p].y, d1[p].x, d1[p].y};
        half8 b = *(half8*)&braw;
        acc = __builtin_amdgcn_mfma_f32_32x32x16_f16(a[p], b, acc, 0, 0, 0);
    }
    int r = z - zstart + r0;
    int ob = ((r * 130 + (y + 1)) * 130 + (x + 1)) * 32;
#pragma unroll
    for (int g = 0; g < 4; ++g) {
        int cb = 4 * lh + 8 * g;
        float4 bt = *(const float4*)(beta + cb);
        ushort4 u;
        u.x = f2bf(fmaxf(acc[g * 4 + 0] + bt.x, 0.f));
        u.y = f2bf(fmaxf(acc[g * 4 + 1] + bt.y, 0.f));
        u.z = f2bf(fmaxf(acc[g * 4 + 2] + bt.z, 0.f));
        u.w = f2bf(fmaxf(acc[g * 4 + 3] + bt.w, 0.f));
        *(ushort4*)(out + ob + cb) = u;
    }
}

// ---------------- convs 2-6: MFMA implicit GEMM, LDS double-buffer + reg prefetch ----------------
// 256 thr = 4 waves, tile 64co x 128vox; each wave: 64co x 32vox (2 acc tiles).
// Pipeline: step s issues global loads for stage s+2 (regs), computes stage s from LDS buf s&1,
// dumps stage s+1 regs into buf (s+1)&1, then lgkm-only barrier (vmcnt stays live across it).
template <int CI, int KC, int S>
__global__ __launch_bounds__(256) void conv_mfma(
    const unsigned short* __restrict__ in, const unsigned short* __restrict__ wb,
    const float* __restrict__ beta, unsigned short* __restrict__ out,
    int D, int lgD, int Xp, int Xpo, int Co, int zin_base, int v_off) {

    constexpr int KCp = KC + 8;      // LDS row pad: 2-way bank aliasing (free)
    constexpr int OPB = KC / 8;      // 16B octets per vox row
    constexpr int NB = KC / 16;      // B reg slots per thread
    constexpr int NA = KC / 32;      // A reg slots per thread
    constexpr int NCH = KC / 16;     // MFMA k16-chunks per stage
    constexpr int NCC = CI / KC;     // stages per k-offset
    constexpr int STOT = 27 * NCC;

    __shared__ __align__(16) short sA[2 * 64 * KCp];
    __shared__ __align__(16) short sB[2 * 128 * KCp];

    const int tid = threadIdx.x;
    const int l31 = tid & 31;
    const int lh = (tid >> 5) & 1;
    const int wv = tid >> 6;
    const int co0 = blockIdx.x * 64;

    // B staging addresses
    int bgIdx[NB], blB[NB];
#pragma unroll
    for (int j = 0; j < NB; ++j) {
        int idx = tid + j * 256;
        int vL = idx / OPB;
        int oct = idx - vL * OPB;
        int vg = v_off + blockIdx.y * 128 + vL;
        int x = vg & (D - 1);
        int ry = vg >> lgD;
        int y = ry & (D - 1);
        int z = ry >> lgD;
        bgIdx[j] = ((z * S * Xp + y * S) * Xp + x * S) * CI + oct * 8;
        blB[j] = vL * KCp + oct * 8;
    }
    // A staging addresses
    int agIdx[NA], alA[NA];
#pragma unroll
    for (int j = 0; j < NA; ++j) {
        int idx = tid + j * 256;
        int cA = idx / OPB;
        int oct = idx - cA * OPB;
        agIdx[j] = (co0 + cA) * CI + oct * 8;
        alA[j] = cA * KCp + oct * 8;
    }
    const int bfr = (wv * 32 + l31) * KCp + lh * 8;
    const int afr = l31 * KCp + lh * 8;

    short8 rB[2][NB], rA[2][NA];

    auto loadStage = [&](int s, int r) {
        int k = s / NCC;
        int c0 = (s - k * NCC) * KC;
        int dz = k / 9;
        int rr = k - dz * 9;
        int dy = rr / 3;
        int dx = rr - dy * 3;
        int kb = (((dz - zin_base) * Xp + dy) * Xp + dx) * CI + c0;
        int ka = k * Co * CI + c0;
#pragma unroll
        for (int j = 0; j < NB; ++j) rB[r][j] = *(const short8*)(in + bgIdx[j] + kb);
#pragma unroll
        for (int j = 0; j < NA; ++j) rA[r][j] = *(const short8*)(wb + agIdx[j] + ka);
    };
    auto storeLDS = [&](int r, int buf) {
#pragma unroll
        for (int j = 0; j < NB; ++j) *(short8*)(sB + buf * 128 * KCp + blB[j]) = rB[r][j];
#pragma unroll
        for (int j = 0; j < NA; ++j) *(short8*)(sA + buf * 64 * KCp + alA[j]) = rA[r][j];
    };

    f32x16 acc0 = {0.f}, acc1 = {0.f};

    loadStage(0, 0);
    loadStage(1, 1);
    storeLDS(0, 0);
    sync_lds();

#pragma unroll
    for (int s = 0; s < STOT; ++s) {
        if (s + 2 < STOT) loadStage(s + 2, s & 1);
        const short* pB = sB + (s & 1) * 128 * KCp + bfr;
        const short* pA = sA + (s & 1) * 64 * KCp + afr;
#pragma unroll
        for (int c = 0; c < NCH; ++c) {
            short8 bv = *(const short8*)(pB + c * 16);
            short8 a0 = *(const short8*)(pA + c * 16);
            short8 a1 = *(const short8*)(pA + 32 * KCp + c * 16);
            acc0 = __builtin_amdgcn_mfma_f32_32x32x16_bf16(a0, bv, acc0, 0, 0, 0);
            acc1 = __builtin_amdgcn_mfma_f32_32x32x16_bf16(a1, bv, acc1, 0, 0, 0);
        }
        if (s + 1 < STOT) {
            storeLDS((s + 1) & 1, (s + 1) & 1);
            sync_lds();
        }
    }

    // epilogue: relu(acc + beta) -> bf16, channels-last padded store (layout verified R4)
    int vg = v_off + blockIdx.y * 128 + wv * 32 + l31;
    int x = vg & (D - 1);
    int ry = vg >> lgD;
    int y = ry & (D - 1);
    int z = ry >> lgD;
    size_t ob = (((size_t)(z + 1) * Xpo + (y + 1)) * Xpo + (x + 1)) * Co + co0;
#pragma unroll
    for (int cot = 0; cot < 2; ++cot) {
        const f32x16& a = cot ? acc1 : acc0;
#pragma unroll
        for (int g = 0; g < 4; ++g) {
            int cb = cot * 32 + 4 * lh + 8 * g;
            float4 bt = *(const float4*)(beta + co0 + cb);
            ushort4 u;
            u.x = f2bf(fmaxf(a[g * 4 + 0] + bt.x, 0.f));
            u.y = f2bf(fmaxf(a[g * 4 + 1] + bt.y, 0.f));
            u.z = f2bf(fmaxf(a[g * 4 + 2] + bt.z, 0.f));
            u.w = f2bf(fmaxf(a[g * 4 + 3] + bt.w, 0.f));
            *(ushort4*)(out + ob + cb) = u;
        }
    }
}

// ---------------- BEV max over y: O6p (34,34,34,256) -> bev[(z*32+x)*256+c] f32 ----------------
__global__ __launch_bounds__(256) void bev_max_kernel(const unsigned short* __restrict__ feat,
                                                      float* __restrict__ bev) {
    int z = blockIdx.x >> 5;
    int x = blockIdx.x & 31;
    int c = threadIdx.x;
    const unsigned short* p = feat + ((((z + 1) * 34) + 1) * 34 + (x + 1)) * 256 + c;
    float mx = 0.f;  // post-ReLU values are >= 0
#pragma unroll
    for (int y = 0; y < 32; ++y) mx = fmaxf(mx, bf2f(p[y * 34 * 256]));
    bev[(z * 32 + x) * 256 + c] = mx;
}

// ---------------- bilinear resize 32x32 -> 200x200, half-pixel, edge clamp ----------------
__global__ __launch_bounds__(256) void resize_kernel(const float* __restrict__ bev,
                                                     float* __restrict__ out) {
    int i = blockIdx.x * 256 + threadIdx.x;
    if (i >= 256 * 200 * 200) return;
    int ox = i % 200;
    int t = i / 200;
    int oy = t % 200;
    int c = t / 200;
    const float sc = 32.0f / 200.0f;
    float fy = (oy + 0.5f) * sc - 0.5f;
    float fx = (ox + 0.5f) * sc - 0.5f;
    float fy0 = floorf(fy), fx0 = floorf(fx);
    float ty = fy - fy0, tx = fx - fx0;
    int y0 = min(max((int)fy0, 0), 31), y1 = min(max((int)fy0 + 1, 0), 31);
    int x0 = min(max((int)fx0, 0), 31), x1 = min(max((int)fx0 + 1, 0), 31);
    float v00 = bev[(y0 * 32 + x0) * 256 + c], v01 = bev[(y0 * 32 + x1) * 256 + c];
    float v10 = bev[(y1 * 32 + x0) * 256 + c], v11 = bev[(y1 * 32 + x1) * 256 + c];
    float top = v00 + tx * (v01 - v00);
    float bot = v10 + tx * (v11 - v10);
    out[i] = top + ty * (bot - top);
}

extern "C" void kernel_launch(void* const* d_in, const int* in_sizes, int n_in,
                              void* d_out, int out_size, void* d_ws, size_t ws_size,
                              hipStream_t stream) {
    const float* points = (const float*)d_in[0];
    int N = in_sizes[0] / 4;
    const float *W[6], *G[6], *B[6];
    for (int i = 0; i < 6; ++i) {
        W[i] = (const float*)d_in[1 + 3 * i];
        G[i] = (const float*)d_in[2 + 3 * i];
        B[i] = (const float*)d_in[3 + 3 * i];
    }

    // ---- workspace layout (bytes), peak ~144 MiB ----
    char* ws = (char*)d_ws;
    const size_t MiB = 1ull << 20;
    unsigned short* gridH = (unsigned short*)(ws);               // f16 (130^3,4) = 17,576,000 B
    unsigned short* O1s = (unsigned short*)(ws + 18 * MiB);      // 65*130*130*32*2 = 70,304,000
    unsigned short* O2p = (unsigned short*)(ws + 104 * MiB);     // 66^3*64*2 = 36,799,488
    unsigned short* O3p = (unsigned short*)(ws);                 // 36,799,488 (over dead gridH/O1s-head)
    unsigned short* O4p = (unsigned short*)(ws + 37 * MiB);      // 34^3*128*2 = 10,061,824
    unsigned short* O5p = (unsigned short*)(ws + 48 * MiB);      // 10,061,824
    unsigned short* O6p = (unsigned short*)(ws + 59 * MiB);      // 34^3*256*2 = 20,123,648
    float* bev = (float*)(ws + 80 * MiB);                        // 1,048,576
    unsigned short* wc1 = (unsigned short*)(ws + 140 * MiB);     // 9*32*16*2 = 9,216
    unsigned short* wb2 = (unsigned short*)(ws + 140 * MiB + 16384);
    unsigned short* wb3 = wb2 + 27 * 64 * 32;
    unsigned short* wb4 = wb3 + 27 * 64 * 64;
    unsigned short* wb5 = wb4 + 27 * 128 * 64;
    unsigned short* wb6 = wb5 + 27 * 128 * 128;

    // weight repacks (independent of activations)
    repack_w1m<<<18, 256, 0, stream>>>(W[0], G[0], wc1);
    repack_w<<<216, 256, 0, stream>>>(W[1], G[1], wb2, 64, 32);
    repack_w<<<432, 256, 0, stream>>>(W[2], G[2], wb3, 64, 64);
    repack_w<<<864, 256, 0, stream>>>(W[3], G[3], wb4, 128, 64);
    repack_w<<<1728, 256, 0, stream>>>(W[4], G[4], wb5, 128, 128);
    repack_w<<<3456, 256, 0, stream>>>(W[5], G[5], wb6, 256, 128);

    // voxelize (f16 pk atomics)
    hipMemsetAsync(gridH, 0, 17576000, stream);
    hipMemsetAsync(O2p, 0, 36799488, stream);
    voxelize_kernel<<<(N + 255) / 256, 256, 0, stream>>>((const float4*)points, (__half2*)gridH, N);

    // conv1/conv2 in two z-slabs (O1s holds 65 padded-z rows)
    hipMemsetAsync(O1s, 0, 70304000, stream);
    conv1_mfma<<<8192, 256, 0, stream>>>(gridH, wc1, B[0], O1s, 0, 1);
    conv_mfma<32, 32, 2><<<dim3(1, 1024), 256, 0, stream>>>(O1s, wb2, B[1], O2p, 64, 6, 130, 66, 64, 0, 0);
    conv1_mfma<<<8320, 256, 0, stream>>>(gridH, wc1, B[0], O1s, 63, 0);
    conv_mfma<32, 32, 2><<<dim3(1, 1024), 256, 0, stream>>>(O1s, wb2, B[1], O2p, 64, 6, 130, 66, 64, 64, 131072);

    // remaining buffers become free only after conv2-h2
    hipMemsetAsync(O3p, 0, 36799488, stream);
    hipMemsetAsync(O4p, 0, 10061824, stream);
    hipMemsetAsync(O5p, 0, 10061824, stream);
    hipMemsetAsync(O6p, 0, 20123648, stream);

    // conv3: 64->64, s1, 64^3
    conv_mfma<64, 64, 1><<<dim3(1, 2048), 256, 0, stream>>>(O2p, wb3, B[2], O3p, 64, 6, 66, 66, 64, 0, 0);
    // conv4: 64->128, s2, 64^3 -> 32^3
    conv_mfma<64, 64, 2><<<dim3(2, 256), 256, 0, stream>>>(O3p, wb4, B[3], O4p, 32, 5, 66, 34, 128, 0, 0);
    // conv5: 128->128, s1, 32^3
    conv_mfma<128, 64, 1><<<dim3(2, 256), 256, 0, stream>>>(O4p, wb5, B[4], O5p, 32, 5, 34, 34, 128, 0, 0);
    // conv6: 128->256, s1, 32^3
    conv_mfma<128, 64, 1><<<dim3(4, 256), 256, 0, stream>>>(O5p, wb6, B[5], O6p, 32, 5, 34, 34, 256, 0, 0);

    bev_max_kernel<<<1024, 256, 0, stream>>>(O6p, bev);
    resize_kernel<<<40000, 256, 0, stream>>>(bev, (float*)d_out);
}